// Round 5
// baseline (324.828 us; speedup 1.0000x reference)
//
#include <hip/hip_runtime.h>

#define NDIM 32
#define EDIM 16
#define NHID 64
#define NIN1 144
#define SCHUNK 1024  // counts per scan block
#define SPT 4        // counts per thread (256 threads/block)

// ---------------------------------------------------------------------------
// 1) Histogram of dst -> counts[N]; first 36 blocks also transpose W1 into
//    W1T[k][r] (contiguous per-k rows for the node kernel's scalar loads).
// ---------------------------------------------------------------------------
__global__ __launch_bounds__(256) void sse_hist(
    const int* __restrict__ dst, int* __restrict__ counts,
    const float* __restrict__ W1, float* __restrict__ W1T, int E) {
  int e = blockIdx.x * 256 + threadIdx.x;
  if (e < NHID * NIN1) {
    int r = e / NIN1, k = e - r * NIN1;
    W1T[k * NHID + r] = W1[e];
  }
  if (e < E) atomicAdd(&counts[dst[e]], 1);
}

// ---------------------------------------------------------------------------
// 2a) Per-block partial sums over 1024-count chunks.
// ---------------------------------------------------------------------------
__global__ __launch_bounds__(256) void sse_scan_part(
    const int* __restrict__ counts, int* __restrict__ bsum, int N) {
  __shared__ int ws[4];
  int t = threadIdx.x;
  int base = blockIdx.x * SCHUNK + t * SPT;
  int s = 0;
#pragma unroll
  for (int i = 0; i < SPT; ++i) {
    int idx = base + i;
    if (idx < N) s += counts[idx];
  }
  int v = s;
#pragma unroll
  for (int off = 1; off < 64; off <<= 1) v += __shfl_xor(v, off, 64);
  if ((t & 63) == 0) ws[t >> 6] = v;
  __syncthreads();
  if (t == 0) bsum[blockIdx.x] = ws[0] + ws[1] + ws[2] + ws[3];
}

// ---------------------------------------------------------------------------
// 2b) Final scan: block sums bsum[j<blk] scalarly, re-scans its chunk,
//     emits starts & cursors. Last block writes starts[N] = E.
// ---------------------------------------------------------------------------
__global__ __launch_bounds__(256) void sse_scan_final(
    const int* __restrict__ counts, const int* __restrict__ bsum,
    int* __restrict__ starts, int* __restrict__ cursors, int N, int nb) {
  __shared__ int ws[4];
  int t = threadIdx.x;
  int lane = t & 63, w = t >> 6;
  int boff = 0;
  for (int j = 0; j < (int)blockIdx.x; ++j) boff += bsum[j];
  int base = blockIdx.x * SCHUNK + t * SPT;
  int c[SPT];
  int s = 0;
#pragma unroll
  for (int i = 0; i < SPT; ++i) {
    int idx = base + i;
    c[i] = (idx < N) ? counts[idx] : 0;
    s += c[i];
  }
  int incl = s;
#pragma unroll
  for (int off = 1; off < 64; off <<= 1) {
    int u = __shfl_up(incl, off, 64);
    if (lane >= off) incl += u;
  }
  if (lane == 63) ws[w] = incl;
  __syncthreads();
  int woff = 0;
#pragma unroll
  for (int j = 0; j < 4; ++j)
    if (j < w) woff += ws[j];
  int run = boff + woff + (incl - s);
#pragma unroll
  for (int i = 0; i < SPT; ++i) {
    int idx = base + i;
    if (idx < N) {
      starts[idx] = run;
      cursors[idx] = run;
      run += c[i];
    }
  }
  if ((int)blockIdx.x == nb - 1 && t == 0)
    starts[N] = boff + ws[0] + ws[1] + ws[2] + ws[3];
}

// ---------------------------------------------------------------------------
// 3) Build sorted edge list: (src, eid) packed as int2, one 8B store.
// ---------------------------------------------------------------------------
__global__ __launch_bounds__(256) void sse_build(
    const int* __restrict__ src, const int* __restrict__ dst,
    int* __restrict__ cursors, int2* __restrict__ sedge, int E) {
  int e = blockIdx.x * 256 + threadIdx.x;
  if (e >= E) return;
  int d = dst[e];
  int pos = atomicAdd(&cursors[d], 1);
  sedge[pos] = make_int2(src[e], e);
}

// ---------------------------------------------------------------------------
// 4) Gather, float4-vectorized: wave per node. For h, lane = (q=edge-in-quad,
//    m=float4-in-row): one instruction covers 4 h-rows. For ef, 16 edges per
//    instruction. Cross-lane shfl_xor reduction at the end. Same bytes as
//    before, ~4x fewer VMEM issues.
// ---------------------------------------------------------------------------
__global__ __launch_bounds__(256) void sse_gather(
    const float* __restrict__ h, const float* __restrict__ ef,
    const int* __restrict__ starts, const int2* __restrict__ sedge,
    float* __restrict__ efsum, float* __restrict__ hsum, int N) {
  int node = blockIdx.x * 4 + (threadIdx.x >> 6);
  int lane = threadIdx.x & 63;
  if (node >= N) return;
  int st = starts[node], en = starts[node + 1];
  const float4* h4 = (const float4*)h;
  const float4* ef4 = (const float4*)ef;

  // ---- h accumulation: q picks edge within quad, m picks float4 in row ----
  int q = lane >> 4, m = lane & 15;
  float4 ha = make_float4(0.f, 0.f, 0.f, 0.f);
  int j = st;
  for (; j + 7 < en; j += 8) {
    int s0 = sedge[j + q].x;
    int s1 = sedge[j + 4 + q].x;
    float4 v0 = h4[(size_t)s0 * 16 + m];
    float4 v1 = h4[(size_t)s1 * 16 + m];
    ha.x += v0.x + v1.x;
    ha.y += v0.y + v1.y;
    ha.z += v0.z + v1.z;
    ha.w += v0.w + v1.w;
  }
  if (j + 3 < en) {
    int s0 = sedge[j + q].x;
    float4 v0 = h4[(size_t)s0 * 16 + m];
    ha.x += v0.x; ha.y += v0.y; ha.z += v0.z; ha.w += v0.w;
    j += 4;
  }
  if (j + q < en) {
    int s0 = sedge[j + q].x;
    float4 v0 = h4[(size_t)s0 * 16 + m];
    ha.x += v0.x; ha.y += v0.y; ha.z += v0.z; ha.w += v0.w;
  }
  // reduce over q (lanes m, m+16, m+32, m+48)
#pragma unroll
  for (int off = 16; off < 64; off <<= 1) {
    ha.x += __shfl_xor(ha.x, off, 64);
    ha.y += __shfl_xor(ha.y, off, 64);
    ha.z += __shfl_xor(ha.z, off, 64);
    ha.w += __shfl_xor(ha.w, off, 64);
  }
  if (lane < 16) ((float4*)hsum)[(size_t)node * 16 + m] = ha;

  // ---- ef accumulation: 16 edges per instruction ----
  int eq = lane >> 2, em = lane & 3;
  float4 ea = make_float4(0.f, 0.f, 0.f, 0.f);
  for (j = st; j + 15 < en; j += 16) {
    int eid = sedge[j + eq].y;
    float4 v = ef4[(size_t)eid * 4 + em];
    ea.x += v.x; ea.y += v.y; ea.z += v.z; ea.w += v.w;
  }
  if (j + eq < en) {
    int eid = sedge[j + eq].y;
    float4 v = ef4[(size_t)eid * 4 + em];
    ea.x += v.x; ea.y += v.y; ea.z += v.z; ea.w += v.w;
  }
#pragma unroll
  for (int off = 4; off < 64; off <<= 1) {
    ea.x += __shfl_xor(ea.x, off, 64);
    ea.y += __shfl_xor(ea.y, off, 64);
    ea.z += __shfl_xor(ea.z, off, 64);
    ea.w += __shfl_xor(ea.w, off, 64);
  }
  if (lane < 4) ((float4*)efsum)[(size_t)node * 4 + em] = ea;
}

// ---------------------------------------------------------------------------
// 5) Node MLP, lane = node, 1-wave blocks, SGPR weights.
//    Weight addresses are wave-uniform -> s_load on the scalar pipe; v_fma
//    takes the SGPR operand directly. Zero LDS traffic for weights.
//    z (144 floats/node) staged in LDS [k4][lane] for dynamic-index reads
//    (36 ds_read_b128/wave). a[64] stays in registers (static indices).
// ---------------------------------------------------------------------------
__global__ __launch_bounds__(64) void sse_node(
    const float* __restrict__ h, const float* __restrict__ nf,
    const float* __restrict__ efsum, const float* __restrict__ hsum,
    const int* __restrict__ starts, const float* __restrict__ W1T,
    const float* __restrict__ W2, float* __restrict__ out, int N) {
  __shared__ float4 zl[36 * 64];  // 36 KB

  int lane = threadIdx.x;
  int node = blockIdx.x * 64 + lane;
  int nodeC = node < N ? node : N - 1;
  int st = starts[nodeC], en = starts[nodeC + 1];
  int dgi = en - st;
  float dg = (float)dgi;

  const float4* nfr = (const float4*)(nf + (size_t)nodeC * NDIM);     // 8
  const float4* efr = (const float4*)(efsum + (size_t)nodeC * EDIM);  // 4
  const float4* hsr = (const float4*)(hsum + (size_t)nodeC * NHID);   // 16

  // z = [nf(0:8) | dg*nf(8:16) | ef(16:20) | hs(20:36)] in float4 units
#pragma unroll
  for (int k4 = 0; k4 < 8; ++k4) {
    float4 v = nfr[k4];
    zl[k4 * 64 + lane] = v;
    zl[(k4 + 8) * 64 + lane] = make_float4(dg * v.x, dg * v.y, dg * v.z, dg * v.w);
  }
#pragma unroll
  for (int k4 = 0; k4 < 4; ++k4) zl[(16 + k4) * 64 + lane] = efr[k4];
#pragma unroll
  for (int k4 = 0; k4 < 16; ++k4) zl[(20 + k4) * 64 + lane] = hsr[k4];
  __syncthreads();

  // ---- layer 1: a[r] = relu(sum_k W1[r][k] z[k]) via W1T[k][r] ----
  float a[64];
#pragma unroll
  for (int r = 0; r < 64; ++r) a[r] = 0.f;

  for (int k4 = 0; k4 < 36; ++k4) {
    float4 zv = zl[k4 * 64 + lane];
    const float* w0 = W1T + (size_t)(4 * k4 + 0) * 64;
    const float* w1 = W1T + (size_t)(4 * k4 + 1) * 64;
    const float* w2 = W1T + (size_t)(4 * k4 + 2) * 64;
    const float* w3 = W1T + (size_t)(4 * k4 + 3) * 64;
#pragma unroll
    for (int r = 0; r < 64; ++r) {
      float t = fmaf(w0[r], zv.x, a[r]);
      t = fmaf(w1[r], zv.y, t);
      t = fmaf(w2[r], zv.z, t);
      a[r] = fmaf(w3[r], zv.w, t);
    }
  }
#pragma unroll
  for (int r = 0; r < 64; ++r) a[r] = fmaxf(a[r], 0.f);

  // ---- layer 2: o[r2] = sum_k W2[r2][k] a[k]; W2 rows contiguous ----
  float4* out4 = (float4*)out;
  for (int r2g = 0; r2g < 16; ++r2g) {
    const float* wr0 = W2 + (size_t)(4 * r2g + 0) * 64;
    const float* wr1 = W2 + (size_t)(4 * r2g + 1) * 64;
    const float* wr2 = W2 + (size_t)(4 * r2g + 2) * 64;
    const float* wr3 = W2 + (size_t)(4 * r2g + 3) * 64;
    float4 o = make_float4(0.f, 0.f, 0.f, 0.f);
#pragma unroll
    for (int k = 0; k < 64; ++k) {
      o.x = fmaf(wr0[k], a[k], o.x);
      o.y = fmaf(wr1[k], a[k], o.y);
      o.z = fmaf(wr2[k], a[k], o.z);
      o.w = fmaf(wr3[k], a[k], o.w);
    }
    if (node < N) out4[(size_t)node * 16 + r2g] = o;
  }

  // deg==0 passthrough (P ~ 1e-7 per node; divergent path almost never taken)
  if (node < N && dgi == 0) {
    const float4* hr = (const float4*)(h + (size_t)node * NHID);
#pragma unroll
    for (int j4 = 0; j4 < 16; ++j4) out4[(size_t)node * 16 + j4] = hr[j4];
  }
}

extern "C" void kernel_launch(void* const* d_in, const int* in_sizes, int n_in,
                              void* d_out, int out_size, void* d_ws, size_t ws_size,
                              hipStream_t stream) {
  const float* h  = (const float*)d_in[0];
  const float* nf = (const float*)d_in[1];
  const float* ef = (const float*)d_in[2];
  const int*   src = (const int*)d_in[3];
  const int*   dst = (const int*)d_in[4];
  const float* W1 = (const float*)d_in[5];
  const float* W2 = (const float*)d_in[6];
  float* out = (float*)d_out;

  int N = in_sizes[0] / NHID;  // h is [N, 64]
  int E = in_sizes[3];         // src is [E]

  // ws layout (bytes):
  // sedge[E] int2 | counts[N] | starts[N+1] | cursors[N] | bsum[64] |
  // W1T[144*64] | pad | efsum[N*16] f | hsum[N*64] f
  char* p = (char*)d_ws;
  int2* sedge = (int2*)p;                 p += (size_t)E * 8;
  int* counts = (int*)p;                  p += (size_t)N * 4;
  int* starts = (int*)p;                  p += (size_t)(N + 1) * 4;
  int* cursors = (int*)p;                 p += (size_t)N * 4;
  int* bsum = (int*)p;                    p += 64 * 4;
  float* W1T = (float*)p;                 p += (size_t)NIN1 * NHID * 4;
  p = (char*)(((size_t)p + 15) & ~(size_t)15);
  float* efsum = (float*)p;               p += (size_t)N * EDIM * 4;
  float* hsum = (float*)p;

  hipMemsetAsync(counts, 0, (size_t)N * sizeof(int), stream);

  int eblocks = (E + 255) / 256;
  int nb = (N + SCHUNK - 1) / SCHUNK;  // 49 for N=50000 (<= 64)

  sse_hist<<<eblocks, 256, 0, stream>>>(dst, counts, W1, W1T, E);
  sse_scan_part<<<nb, 256, 0, stream>>>(counts, bsum, N);
  sse_scan_final<<<nb, 256, 0, stream>>>(counts, bsum, starts, cursors, N, nb);
  sse_build<<<eblocks, 256, 0, stream>>>(src, dst, cursors, sedge, E);

  int gblocks = (N + 3) / 4;
  sse_gather<<<gblocks, 256, 0, stream>>>(h, ef, starts, sedge, efsum, hsum, N);

  int nblocks = (N + 63) / 64;  // 782 one-wave blocks
  sse_node<<<nblocks, 64, 0, stream>>>(h, nf, efsum, hsum, starts, W1T, W2,
                                       out, N);
}

// Round 6
// 273.075 us; speedup vs baseline: 1.1895x; 1.1895x over previous
//
#include <hip/hip_runtime.h>

#define NDIM 32
#define EDIM 16
#define NHID 64
#define NIN1 144
#define SCHUNK 1024  // counts per scan block
#define SPT 4        // counts per thread (256 threads/block)

// ---------------------------------------------------------------------------
// 1) Histogram of dst -> counts[N]; early blocks also transpose W1 -> W1T
//    and W2 -> W2T ([k][r] layout: contiguous 16-float row chunks per k for
//    the node kernel's uniform scalar loads).
// ---------------------------------------------------------------------------
__global__ __launch_bounds__(256) void sse_hist(
    const int* __restrict__ dst, int* __restrict__ counts,
    const float* __restrict__ W1, float* __restrict__ W1T,
    const float* __restrict__ W2, float* __restrict__ W2T, int E) {
  int e = blockIdx.x * 256 + threadIdx.x;
  if (e < NHID * NIN1) {
    int r = e / NIN1, k = e - r * NIN1;
    W1T[k * NHID + r] = W1[e];
  } else if (e < NHID * NIN1 + NHID * NHID) {
    int i = e - NHID * NIN1;
    int r = i >> 6, k = i & 63;
    W2T[k * NHID + r] = W2[i];
  }
  if (e < E) atomicAdd(&counts[dst[e]], 1);
}

// ---------------------------------------------------------------------------
// 2a) Per-block partial sums over 1024-count chunks.
// ---------------------------------------------------------------------------
__global__ __launch_bounds__(256) void sse_scan_part(
    const int* __restrict__ counts, int* __restrict__ bsum, int N) {
  __shared__ int ws[4];
  int t = threadIdx.x;
  int base = blockIdx.x * SCHUNK + t * SPT;
  int s = 0;
#pragma unroll
  for (int i = 0; i < SPT; ++i) {
    int idx = base + i;
    if (idx < N) s += counts[idx];
  }
  int v = s;
#pragma unroll
  for (int off = 1; off < 64; off <<= 1) v += __shfl_xor(v, off, 64);
  if ((t & 63) == 0) ws[t >> 6] = v;
  __syncthreads();
  if (t == 0) bsum[blockIdx.x] = ws[0] + ws[1] + ws[2] + ws[3];
}

// ---------------------------------------------------------------------------
// 2b) Final scan: block sums bsum[j<blk] scalarly, re-scans its chunk,
//     emits starts & cursors. Last block writes starts[N] = E.
// ---------------------------------------------------------------------------
__global__ __launch_bounds__(256) void sse_scan_final(
    const int* __restrict__ counts, const int* __restrict__ bsum,
    int* __restrict__ starts, int* __restrict__ cursors, int N, int nb) {
  __shared__ int ws[4];
  int t = threadIdx.x;
  int lane = t & 63, w = t >> 6;
  int boff = 0;
  for (int j = 0; j < (int)blockIdx.x; ++j) boff += bsum[j];
  int base = blockIdx.x * SCHUNK + t * SPT;
  int c[SPT];
  int s = 0;
#pragma unroll
  for (int i = 0; i < SPT; ++i) {
    int idx = base + i;
    c[i] = (idx < N) ? counts[idx] : 0;
    s += c[i];
  }
  int incl = s;
#pragma unroll
  for (int off = 1; off < 64; off <<= 1) {
    int u = __shfl_up(incl, off, 64);
    if (lane >= off) incl += u;
  }
  if (lane == 63) ws[w] = incl;
  __syncthreads();
  int woff = 0;
#pragma unroll
  for (int j = 0; j < 4; ++j)
    if (j < w) woff += ws[j];
  int run = boff + woff + (incl - s);
#pragma unroll
  for (int i = 0; i < SPT; ++i) {
    int idx = base + i;
    if (idx < N) {
      starts[idx] = run;
      cursors[idx] = run;
      run += c[i];
    }
  }
  if ((int)blockIdx.x == nb - 1 && t == 0)
    starts[N] = boff + ws[0] + ws[1] + ws[2] + ws[3];
}

// ---------------------------------------------------------------------------
// 3) Build sorted edge list: (src, eid) packed as int2, one 8B store.
// ---------------------------------------------------------------------------
__global__ __launch_bounds__(256) void sse_build(
    const int* __restrict__ src, const int* __restrict__ dst,
    int* __restrict__ cursors, int2* __restrict__ sedge, int E) {
  int e = blockIdx.x * 256 + threadIdx.x;
  if (e >= E) return;
  int d = dst[e];
  int pos = atomicAdd(&cursors[d], 1);
  sedge[pos] = make_int2(src[e], e);
}

// ---------------------------------------------------------------------------
// 4) Gather, float4-vectorized (unchanged from R5 — passed).
// ---------------------------------------------------------------------------
__global__ __launch_bounds__(256) void sse_gather(
    const float* __restrict__ h, const float* __restrict__ ef,
    const int* __restrict__ starts, const int2* __restrict__ sedge,
    float* __restrict__ efsum, float* __restrict__ hsum, int N) {
  int node = blockIdx.x * 4 + (threadIdx.x >> 6);
  int lane = threadIdx.x & 63;
  if (node >= N) return;
  int st = starts[node], en = starts[node + 1];
  const float4* h4 = (const float4*)h;
  const float4* ef4 = (const float4*)ef;

  int q = lane >> 4, m = lane & 15;
  float4 ha = make_float4(0.f, 0.f, 0.f, 0.f);
  int j = st;
  for (; j + 7 < en; j += 8) {
    int s0 = sedge[j + q].x;
    int s1 = sedge[j + 4 + q].x;
    float4 v0 = h4[(size_t)s0 * 16 + m];
    float4 v1 = h4[(size_t)s1 * 16 + m];
    ha.x += v0.x + v1.x;
    ha.y += v0.y + v1.y;
    ha.z += v0.z + v1.z;
    ha.w += v0.w + v1.w;
  }
  if (j + 3 < en) {
    int s0 = sedge[j + q].x;
    float4 v0 = h4[(size_t)s0 * 16 + m];
    ha.x += v0.x; ha.y += v0.y; ha.z += v0.z; ha.w += v0.w;
    j += 4;
  }
  if (j + q < en) {
    int s0 = sedge[j + q].x;
    float4 v0 = h4[(size_t)s0 * 16 + m];
    ha.x += v0.x; ha.y += v0.y; ha.z += v0.z; ha.w += v0.w;
  }
#pragma unroll
  for (int off = 16; off < 64; off <<= 1) {
    ha.x += __shfl_xor(ha.x, off, 64);
    ha.y += __shfl_xor(ha.y, off, 64);
    ha.z += __shfl_xor(ha.z, off, 64);
    ha.w += __shfl_xor(ha.w, off, 64);
  }
  if (lane < 16) ((float4*)hsum)[(size_t)node * 16 + m] = ha;

  int eq = lane >> 2, em = lane & 3;
  float4 ea = make_float4(0.f, 0.f, 0.f, 0.f);
  for (j = st; j + 15 < en; j += 16) {
    int eid = sedge[j + eq].y;
    float4 v = ef4[(size_t)eid * 4 + em];
    ea.x += v.x; ea.y += v.y; ea.z += v.z; ea.w += v.w;
  }
  if (j + eq < en) {
    int eid = sedge[j + eq].y;
    float4 v = ef4[(size_t)eid * 4 + em];
    ea.x += v.x; ea.y += v.y; ea.z += v.z; ea.w += v.w;
  }
#pragma unroll
  for (int off = 4; off < 64; off <<= 1) {
    ea.x += __shfl_xor(ea.x, off, 64);
    ea.y += __shfl_xor(ea.y, off, 64);
    ea.z += __shfl_xor(ea.z, off, 64);
    ea.w += __shfl_xor(ea.w, off, 64);
  }
  if (lane < 4) ((float4*)efsum)[(size_t)node * 4 + em] = ea;
}

// ---------------------------------------------------------------------------
// 5) Node MLP. Block = 256 thr = 4 waves = 64 nodes (lane=node). Wave w
//    computes output rows [16w,16w+16) for all 64 nodes. Per-k weight chunk
//    = 16 floats at uniform address (w via readfirstlane) -> scalar loads on
//    the scalar pipe, SGPR operands into v_fma. 3128 waves total (~3/SIMD).
//    z staged in LDS [k4][node] float4 (stride-16B across lanes: conflict-
//    free); layer1->layer2 activations exchanged via as[kq][node] float4.
// ---------------------------------------------------------------------------
__global__ __launch_bounds__(256) void sse_node(
    const float* __restrict__ h, const float* __restrict__ nf,
    const float* __restrict__ efsum, const float* __restrict__ hsum,
    const int* __restrict__ starts, const float* __restrict__ W1T,
    const float* __restrict__ W2T, float* __restrict__ out, int N) {
  __shared__ float4 zs[36 * 64];  // 36 KB: z (f4 units) [k4][node]
  __shared__ float4 as[16 * 64];  // 16 KB: relu acts [kq][node]

  int tid = threadIdx.x;
  int lane = tid & 63;  // node within block
  int w = __builtin_amdgcn_readfirstlane(tid) >> 6;  // wave id, uniform

  int node = blockIdx.x * 64 + lane;
  int nodeC = node < N ? node : N - 1;

  // ---- stage z: z = [nf(0:8) | dg*nf(8:16) | ef(16:20) | hs(20:36)] f4 ----
  if (w == 0) {
    int st = starts[nodeC], en = starts[nodeC + 1];
    float dg = (float)(en - st);
    const float4* nfr = (const float4*)(nf + (size_t)nodeC * NDIM);
#pragma unroll
    for (int k4 = 0; k4 < 8; ++k4) {
      float4 v = nfr[k4];
      zs[k4 * 64 + lane] = v;
      zs[(8 + k4) * 64 + lane] =
          make_float4(dg * v.x, dg * v.y, dg * v.z, dg * v.w);
    }
  } else if (w == 1) {
    const float4* efr = (const float4*)(efsum + (size_t)nodeC * EDIM);
#pragma unroll
    for (int k4 = 0; k4 < 4; ++k4) zs[(16 + k4) * 64 + lane] = efr[k4];
  } else if (w == 2) {
    const float4* hsr = (const float4*)(hsum + (size_t)nodeC * NHID);
#pragma unroll
    for (int k4 = 0; k4 < 8; ++k4) zs[(20 + k4) * 64 + lane] = hsr[k4];
  } else {
    const float4* hsr = (const float4*)(hsum + (size_t)nodeC * NHID);
#pragma unroll
    for (int k4 = 8; k4 < 16; ++k4) zs[(20 + k4) * 64 + lane] = hsr[k4];
  }
  __syncthreads();

  // ---- layer 1: a[j] = relu(sum_k W1[16w+j][k] z[k]) via W1T[k][r] ----
  const float4* w1b = (const float4*)W1T + w * 4;  // row chunk base (f4)
  float a[16];
#pragma unroll
  for (int j = 0; j < 16; ++j) a[j] = 0.f;

#pragma unroll 2
  for (int k4 = 0; k4 < 36; ++k4) {
    float4 zv = zs[k4 * 64 + lane];
#pragma unroll
    for (int kk = 0; kk < 4; ++kk) {
      int k = k4 * 4 + kk;
      float4 w0 = w1b[k * 16 + 0];
      float4 w1 = w1b[k * 16 + 1];
      float4 w2 = w1b[k * 16 + 2];
      float4 w3 = w1b[k * 16 + 3];
      float zk = kk == 0 ? zv.x : kk == 1 ? zv.y : kk == 2 ? zv.z : zv.w;
      a[0]  = fmaf(w0.x, zk, a[0]);
      a[1]  = fmaf(w0.y, zk, a[1]);
      a[2]  = fmaf(w0.z, zk, a[2]);
      a[3]  = fmaf(w0.w, zk, a[3]);
      a[4]  = fmaf(w1.x, zk, a[4]);
      a[5]  = fmaf(w1.y, zk, a[5]);
      a[6]  = fmaf(w1.z, zk, a[6]);
      a[7]  = fmaf(w1.w, zk, a[7]);
      a[8]  = fmaf(w2.x, zk, a[8]);
      a[9]  = fmaf(w2.y, zk, a[9]);
      a[10] = fmaf(w2.z, zk, a[10]);
      a[11] = fmaf(w2.w, zk, a[11]);
      a[12] = fmaf(w3.x, zk, a[12]);
      a[13] = fmaf(w3.y, zk, a[13]);
      a[14] = fmaf(w3.z, zk, a[14]);
      a[15] = fmaf(w3.w, zk, a[15]);
    }
  }

  // relu + exchange: wave w owns k-range [16w,16w+16) = f4 quads w*4..w*4+3
#pragma unroll
  for (int j4 = 0; j4 < 4; ++j4)
    as[(w * 4 + j4) * 64 + lane] =
        make_float4(fmaxf(a[j4 * 4 + 0], 0.f), fmaxf(a[j4 * 4 + 1], 0.f),
                    fmaxf(a[j4 * 4 + 2], 0.f), fmaxf(a[j4 * 4 + 3], 0.f));
  __syncthreads();

  // ---- layer 2: o[j] = sum_k W2[16w+j][k] act[k] via W2T[k][r] ----
  const float4* w2b = (const float4*)W2T + w * 4;
  float o[16];
#pragma unroll
  for (int j = 0; j < 16; ++j) o[j] = 0.f;

#pragma unroll 2
  for (int kq = 0; kq < 16; ++kq) {
    float4 av = as[kq * 64 + lane];
#pragma unroll
    for (int kk = 0; kk < 4; ++kk) {
      int k = kq * 4 + kk;
      float4 w0 = w2b[k * 16 + 0];
      float4 w1 = w2b[k * 16 + 1];
      float4 w2 = w2b[k * 16 + 2];
      float4 w3 = w2b[k * 16 + 3];
      float ak = kk == 0 ? av.x : kk == 1 ? av.y : kk == 2 ? av.z : av.w;
      o[0]  = fmaf(w0.x, ak, o[0]);
      o[1]  = fmaf(w0.y, ak, o[1]);
      o[2]  = fmaf(w0.z, ak, o[2]);
      o[3]  = fmaf(w0.w, ak, o[3]);
      o[4]  = fmaf(w1.x, ak, o[4]);
      o[5]  = fmaf(w1.y, ak, o[5]);
      o[6]  = fmaf(w1.z, ak, o[6]);
      o[7]  = fmaf(w1.w, ak, o[7]);
      o[8]  = fmaf(w2.x, ak, o[8]);
      o[9]  = fmaf(w2.y, ak, o[9]);
      o[10] = fmaf(w2.z, ak, o[10]);
      o[11] = fmaf(w2.w, ak, o[11]);
      o[12] = fmaf(w3.x, ak, o[12]);
      o[13] = fmaf(w3.y, ak, o[13]);
      o[14] = fmaf(w3.z, ak, o[14]);
      o[15] = fmaf(w3.w, ak, o[15]);
    }
  }

  // ---- store rows [16w,16w+16) of node; deg==0 passthrough (rare) ----
  if (node < N) {
    int st = starts[node], en = starts[node + 1];
    float4* o4 = (float4*)(out + (size_t)node * NHID + w * 16);
    if (en - st == 0) {
      const float4* hr = (const float4*)(h + (size_t)node * NHID + w * 16);
#pragma unroll
      for (int j4 = 0; j4 < 4; ++j4) o4[j4] = hr[j4];
    } else {
#pragma unroll
      for (int j4 = 0; j4 < 4; ++j4)
        o4[j4] = make_float4(o[j4 * 4 + 0], o[j4 * 4 + 1], o[j4 * 4 + 2],
                             o[j4 * 4 + 3]);
    }
  }
}

extern "C" void kernel_launch(void* const* d_in, const int* in_sizes, int n_in,
                              void* d_out, int out_size, void* d_ws, size_t ws_size,
                              hipStream_t stream) {
  const float* h  = (const float*)d_in[0];
  const float* nf = (const float*)d_in[1];
  const float* ef = (const float*)d_in[2];
  const int*   src = (const int*)d_in[3];
  const int*   dst = (const int*)d_in[4];
  const float* W1 = (const float*)d_in[5];
  const float* W2 = (const float*)d_in[6];
  float* out = (float*)d_out;

  int N = in_sizes[0] / NHID;  // h is [N, 64]
  int E = in_sizes[3];         // src is [E]

  // ws layout (bytes):
  // sedge[E] int2 | counts[N] | starts[N+1] | cursors[N] | bsum[64] |
  // W1T[144*64] | W2T[64*64] | pad16 | efsum[N*16] | hsum[N*64]
  char* p = (char*)d_ws;
  int2* sedge = (int2*)p;                 p += (size_t)E * 8;
  int* counts = (int*)p;                  p += (size_t)N * 4;
  int* starts = (int*)p;                  p += (size_t)(N + 1) * 4;
  int* cursors = (int*)p;                 p += (size_t)N * 4;
  int* bsum = (int*)p;                    p += 64 * 4;
  float* W1T = (float*)p;                 p += (size_t)NIN1 * NHID * 4;
  float* W2T = (float*)p;                 p += (size_t)NHID * NHID * 4;
  p = (char*)(((size_t)p + 15) & ~(size_t)15);
  float* efsum = (float*)p;               p += (size_t)N * EDIM * 4;
  float* hsum = (float*)p;

  hipMemsetAsync(counts, 0, (size_t)N * sizeof(int), stream);

  int eblocks = (E + 255) / 256;
  int nb = (N + SCHUNK - 1) / SCHUNK;  // 49 for N=50000 (<= 64)

  sse_hist<<<eblocks, 256, 0, stream>>>(dst, counts, W1, W1T, W2, W2T, E);
  sse_scan_part<<<nb, 256, 0, stream>>>(counts, bsum, N);
  sse_scan_final<<<nb, 256, 0, stream>>>(counts, bsum, starts, cursors, N, nb);
  sse_build<<<eblocks, 256, 0, stream>>>(src, dst, cursors, sedge, E);

  int gblocks = (N + 3) / 4;
  sse_gather<<<gblocks, 256, 0, stream>>>(h, ef, starts, sedge, efsum, hsum, N);

  int nblocks = (N + 63) / 64;  // 782 blocks x 4 waves = 3128 waves
  sse_node<<<nblocks, 256, 0, stream>>>(h, nf, efsum, hsum, starts, W1T, W2T,
                                        out, N);
}